// Round 16
// baseline (143.246 us; speedup 1.0000x reference)
//
#include <hip/hip_runtime.h>
#include <hip/hip_bf16.h>

// XConv: N=32 P=1024 K=16 DIMS=3 C_IN=64 C_MID=64 C_OUT=128 DM=2; NP=32768
// ws layout: [0, 16.8MB) x2 bf16 ; [32MB, 48.8MB) tmp bf16. No aliasing.

#define ELU(x) ((x) > 0.0f ? (x) : (__expf(x) - 1.0f))

__device__ __forceinline__ void lds_fence() {
    asm volatile("s_waitcnt lgkmcnt(0)" ::: "memory");
}

typedef __attribute__((ext_vector_type(8))) short short8v;
typedef __attribute__((ext_vector_type(4))) float f32x4;
typedef __attribute__((ext_vector_type(2))) unsigned int uint2v;
#define MFMA32(a, b, c) __builtin_amdgcn_mfma_f32_16x16x32_bf16(a, b, c, 0, 0, 0)

__device__ __forceinline__ short f2bf(float x) {
    __hip_bfloat16 h = __float2bfloat16(x);
    return *reinterpret_cast<short*>(&h);
}
__device__ __forceinline__ float bf2f(short x) {
    unsigned u = ((unsigned)(unsigned short)x) << 16;
    return __uint_as_float(u);
}
__device__ __forceinline__ unsigned packbf(float a, float b) {
    return (unsigned)(unsigned short)f2bf(a) | (((unsigned)(unsigned short)f2bf(b)) << 16);
}
__device__ __forceinline__ void gload_lds16(const float* g, float* l) {
    __builtin_amdgcn_global_load_lds(
        (const __attribute__((address_space(1))) void*)g,
        (__attribute__((address_space(3))) void*)l,
        16, 0, 0);
}
// full xor-32 exchange+add, pure VALU
__device__ __forceinline__ float xor32_add(float q) {
    uint2v r = __builtin_amdgcn_permlane32_swap(__float_as_uint(q), __float_as_uint(q), false, false);
    return __uint_as_float(r.x) + __uint_as_float(r.y);
}

// ---------------- Kernel 1: X-transform via MFMA (bf16 X2 output) ----------------
#define XW_WC   0        // bf16 frag entries: idx=(part*16+u)*64+lane, 16B each (8192 words)
#define XW_WD1  8192     // wdep1: i*260 + j*16 + k  (4160 words)
#define XW_WD2  12352    // wdep2 same               (4160)
#define XW_BC   16512    // bconv 256
#define XW_BD1  16768    // 256
#define XW_BD2  17024    // 256
#define XW_SCR  17280    // + wave*4368 : per-point stride 273, scr[p*273 + j*17 + s]
#define XW_TOTAL (17280 + 4*4368)   // 34752 words = 139008 B

__global__ __launch_bounds__(256) void k_xform(
    const float* __restrict__ rep, const float* __restrict__ pts,
    const float* __restrict__ wconv, const float* __restrict__ bconv,
    const float* __restrict__ wdep1, const float* __restrict__ bdep1,
    const float* __restrict__ wdep2, const float* __restrict__ bdep2,
    unsigned short* __restrict__ x2bf)
{
    extern __shared__ __align__(16) float sm[];
    short* smh = (short*)sm;
    const int tid = threadIdx.x;

    for (int e = tid; e < 2048; e += 256) {
        const int part = e >> 10, u = (e >> 6) & 15, l = e & 63;
        const int g = l >> 4, s = l & 15;
        const int o = u * 16 + s;
        short8v v;
        if (part == 0) {
            #pragma unroll
            for (int t = 0; t < 8; ++t) v[t] = f2bf(wconv[o*48 + g*8 + t]);
        } else {
            #pragma unroll
            for (int t = 0; t < 4; ++t) v[t] = f2bf(wconv[o*48 + 32 + g*4 + t]);
            #pragma unroll
            for (int t = 4; t < 8; ++t) v[t] = 0;
        }
        *(short8v*)&smh[e * 8] = v;
    }
    for (int e = tid; e < 4096; e += 256) {
        const int i = e >> 8, j = (e >> 4) & 15, k = e & 15;
        sm[XW_WD1 + i*260 + j*16 + k] = wdep1[e];
        sm[XW_WD2 + i*260 + j*16 + k] = wdep2[e];
    }
    sm[XW_BC  + tid] = bconv[tid];
    sm[XW_BD1 + tid] = bdep1[tid];
    sm[XW_BD2 + tid] = bdep2[tid];
    __syncthreads();

    const int wave = tid >> 6, lane = tid & 63;
    const int g = lane >> 4, s = lane & 15;
    const int pt0 = (blockIdx.x * 4 + wave) * 16;

    const int p = pt0 + s;
    const float r0 = rep[p*3], r1 = rep[p*3+1], r2 = rep[p*3+2];
    short8v ah0, al0, ah1, al1;
    #pragma unroll
    for (int e = 0; e < 8; ++e) {
        const int r = g*8 + e;
        const int d = g >> 1, k = r & 15;
        const float v = pts[p*48 + k*3 + d] - (d == 0 ? r0 : r1);
        const short h = f2bf(v);
        ah0[e] = h; al0[e] = f2bf(v - bf2f(h));
    }
    #pragma unroll
    for (int e = 0; e < 4; ++e) {
        const int k = g*4 + e;
        const float v = pts[p*48 + k*3 + 2] - r2;
        const short h = f2bf(v);
        ah1[e] = h; al1[e] = f2bf(v - bf2f(h));
    }
    #pragma unroll
    for (int e = 4; e < 8; ++e) { ah1[e] = 0; al1[e] = 0; }

    f32x4 ex[16];
    #pragma unroll
    for (int u = 0; u < 16; ++u) {
        const float b = sm[XW_BC + u*16 + s];
        f32x4 acc; acc[0] = b; acc[1] = b; acc[2] = b; acc[3] = b;
        const short8v bh0 = *(const short8v*)&smh[(u*64 + lane) * 8];
        const short8v bh1 = *(const short8v*)&smh[((16 + u)*64 + lane) * 8];
        acc = MFMA32(ah0, bh0, acc);
        acc = MFMA32(ah1, bh1, acc);
        acc = MFMA32(al0, bh0, acc);
        acc = MFMA32(al1, bh1, acc);
        f32x4 r;
        r[0] = ELU(acc[0]); r[1] = ELU(acc[1]); r[2] = ELU(acc[2]); r[3] = ELU(acc[3]);
        ex[u] = r;
    }

    const int scrb = XW_SCR + wave * 4368;
    #pragma unroll
    for (int j = 0; j < 16; ++j) {
        const float b = sm[XW_BD1 + s*16 + j];
        f32x4 a; a[0] = b; a[1] = b; a[2] = b; a[3] = b;
        #pragma unroll
        for (int kb = 0; kb < 4; ++kb) {
            const float4 w = *(const float4*)&sm[XW_WD1 + s*260 + j*16 + kb*4];
            a += ex[kb*4+0] * w.x; a += ex[kb*4+1] * w.y;
            a += ex[kb*4+2] * w.z; a += ex[kb*4+3] * w.w;
        }
        #pragma unroll
        for (int q = 0; q < 4; ++q)
            sm[scrb + (g*4+q)*273 + j*17 + s] = ELU(a[q]);
    }
    lds_fence();

    f32x4 xr[16];
    #pragma unroll
    for (int k = 0; k < 16; ++k) {
        f32x4 v;
        #pragma unroll
        for (int q = 0; q < 4; ++q)
            v[q] = sm[scrb + (g*4+q)*273 + s*17 + k];
        xr[k] = v;
    }
    f32x4 oj[16];
    #pragma unroll
    for (int j = 0; j < 16; ++j) {
        const float b = sm[XW_BD2 + s*16 + j];
        f32x4 a; a[0] = b; a[1] = b; a[2] = b; a[3] = b;
        #pragma unroll
        for (int kb = 0; kb < 4; ++kb) {
            const float4 w = *(const float4*)&sm[XW_WD2 + s*260 + j*16 + kb*4];
            a += xr[kb*4+0] * w.x; a += xr[kb*4+1] * w.y;
            a += xr[kb*4+2] * w.z; a += xr[kb*4+3] * w.w;
        }
        oj[j] = a;
    }
    #pragma unroll
    for (int q = 0; q < 4; ++q) {
        const int pp = pt0 + g*4 + q;
        #pragma unroll
        for (int jb = 0; jb < 4; ++jb) {
            uint2 pk;
            pk.x = packbf(oj[jb*4+0][q], oj[jb*4+1][q]);
            pk.y = packbf(oj[jb*4+2][q], oj[jb*4+3][q]);
            *(uint2*)&x2bf[(size_t)pp*256 + s*16 + jb*4] = pk;
        }
    }
}

// ---------------- Kernel 2: MFMA features; 512-thr blocks, 16 waves/CU ----------
// 8 waves/block, LDS 73.7KB -> 2 blocks/CU resident = 4 waves/SIMD (was 3).
// launch_bounds(512,4): 128-reg cap; body now ~105-115 regs (fr arrays long gone) -> fits.
// Grid 512, TOTW 4096 -> exactly 8 pts/wave, no tail. Pipeline unchanged from R15.
#define NPTS 32768
#define TOTW 4096
__global__ __launch_bounds__(512, 4) void k_feat(
    const float* __restrict__ rep, const float* __restrict__ pts, const float* __restrict__ fts,
    const float* __restrict__ w1, const float* __restrict__ b1,
    const float* __restrict__ w2, const float* __restrict__ b2,
    const float* __restrict__ wdw, const float* __restrict__ bdw,
    const unsigned short* __restrict__ x2bf, unsigned short* __restrict__ tmpbf)
{
    __shared__ __align__(16) short sw2[4096];      // B-frags: rec r=nt*2+h, 16B @ (r*64+lane)
    __shared__ __align__(16) uint2 sw1[64];        // j: {pack(w1[0][j],w1[1][j]), pack(w1[2][j],b1[j])}
    __shared__ float sbdw[256];
    __shared__ __align__(16) float sfts[8][2][1024]; // [wave][buf][fts tile, sigma-swizzled] 64KB
    const int tid = threadIdx.x;

    for (int idx = tid; idx < 512; idx += 512) {   // 512 recs of 8 bf16
        const int r = idx >> 6, l = idx & 63;
        const int nt = r >> 1, h = r & 1, gg = l >> 4, ss = l & 15;
        short8v v;
        #pragma unroll
        for (int e = 0; e < 8; ++e)
            v[e] = f2bf(w2[(h*32 + gg*8 + e)*64 + nt*16 + ss]);
        *(short8v*)&sw2[idx * 8] = v;
    }
    if (tid < 64) {
        const int j = tid;
        uint2 v;
        v.x = packbf(w1[j], w1[64 + j]);
        v.y = packbf(w1[128 + j], b1[j]);
        sw1[j] = v;
    }
    if (tid < 256) sbdw[tid] = bdw[tid];
    __syncthreads();

    const int lane = tid & 63, wave = tid >> 6;
    const int g = lane >> 4, s = lane & 15;
    const int g8 = g * 8;

    float b2c[4];
    #pragma unroll
    for (int nt = 0; nt < 4; ++nt) b2c[nt] = b2[nt*16 + s];

    // ---- wdw -> per-lane regs (bf16 pairs), loop-invariant ----
    uint2 wp0[8], wp1[8];
    #pragma unroll
    for (int u = 0; u < 8; ++u) {
        const int cb = (u*16 + s) * 32 + 4*g;
        wp0[u].x = packbf(wdw[cb + 0],  wdw[cb + 1]);
        wp0[u].y = packbf(wdw[cb + 2],  wdw[cb + 3]);
        wp1[u].x = packbf(wdw[cb + 16], wdw[cb + 17]);
        wp1[u].y = packbf(wdw[cb + 18], wdw[cb + 19]);
    }

    const int gw = blockIdx.x * 8 + wave;   // 0..4095
    float* sf0 = &sfts[wave][0][0];
    float* sf1 = &sfts[wave][1][0];

    // ---- prologue: swizzled DMA pt=gw into buf0; prefetch scalars(gw) ----
    {
        const float* base = fts + (size_t)gw * 1024;
        #pragma unroll
        for (int i = 0; i < 4; ++i)
            gload_lds16(base + i*256 + (lane ^ (2*i))*4, sf0 + i*256);
    }
    ushort4 xv_n = *(const ushort4*)&x2bf[(size_t)gw*256 + s*16 + g*4];
    float p0_n = pts[gw*48 + s*3 + 0] - rep[gw*3 + 0];
    float p1_n = pts[gw*48 + s*3 + 1] - rep[gw*3 + 1];
    float p2_n = pts[gw*48 + s*3 + 2] - rep[gw*3 + 2];

    int k = 0;
    for (int pt = gw; pt < NPTS; pt += TOTW, ++k) {
        float* sfc = (k & 1) ? sf1 : sf0;
        float* sfn = (k & 1) ? sf0 : sf1;
        const int ptn = pt + TOTW;

        // ---- step 1: issue swizzled DMA(ptn) ----
        if (ptn < NPTS) {
            const float* base = fts + (size_t)ptn * 1024;
            #pragma unroll
            for (int i = 0; i < 4; ++i)
                gload_lds16(base + i*256 + (lane ^ (2*i))*4, sfn + i*256);
        }
        // ---- step 2: counted wait — retires DMA(pt)+scalars(pt), not stores/fresh ----
        asm volatile("s_waitcnt vmcnt(11)" ::: "memory");

        const ushort4 xv = xv_n;
        const float p0 = p0_n, p1 = p1_n, p2 = p2_n;

        // ---- step 3: scalar prefetch(ptn) ----
        if (ptn < NPTS) {
            xv_n = *(const ushort4*)&x2bf[(size_t)ptn*256 + s*16 + g*4];
            p0_n = pts[ptn*48 + s*3 + 0] - rep[ptn*3 + 0];
            p1_n = pts[ptn*48 + s*3 + 1] - rep[ptn*3 + 1];
            p2_n = pts[ptn*48 + s*3 + 2] - rep[ptn*3 + 2];
        }

        // ---- phase A: h1 in A-frag layout; h2 via 8 MFMA ----
        short8v af0, af1;
        #pragma unroll
        for (int t = 0; t < 2; ++t) {
            short8v f;
            #pragma unroll
            for (int e = 0; e < 8; ++e) {
                const uint2 pk = sw1[t*32 + g*8 + e];
                const float wx = __uint_as_float(pk.x << 16);
                const float wy = __uint_as_float(pk.x & 0xffff0000u);
                const float wz = __uint_as_float(pk.y << 16);
                const float bb = __uint_as_float(pk.y & 0xffff0000u);
                float h = bb + p0*wx + p1*wy + p2*wz;
                h = ELU(h);
                f[e] = f2bf(h);
            }
            if (t == 0) af0 = f; else af1 = f;
        }
        f32x4 hacc[4];
        #pragma unroll
        for (int nt = 0; nt < 4; ++nt) {
            f32x4 a; a[0] = b2c[nt]; a[1] = b2c[nt]; a[2] = b2c[nt]; a[3] = b2c[nt];
            const short8v bf0 = *(const short8v*)&sw2[((nt*2 + 0)*64 + lane) * 8];
            const short8v bf1 = *(const short8v*)&sw2[((nt*2 + 1)*64 + lane) * 8];
            a = MFMA32(af0, bf0, a);
            a = MFMA32(af1, bf1, a);
            hacc[nt] = a;
        }
        short8v a2 = (short8v)0;
        a2[0] = (short)xv.x; a2[1] = (short)xv.y;
        a2[2] = (short)xv.z; a2[3] = (short)xv.w;

        // ---- phase B: software-pipelined (bfrag/MFMA one tile ahead of dot) ----
        f32x4 z; z[0] = 0.f; z[1] = 0.f; z[2] = 0.f; z[3] = 0.f;
        float q0a[8], q1a[8];
        short8v bf_c = (short8v)0;
        #pragma unroll
        for (int q = 0; q < 4; ++q) bf_c[q] = f2bf(ELU(hacc[0][q]));
        f32x4 fx_c = MFMA32(a2, bf_c, z);
        #pragma unroll
        for (int u = 0; u < 8; ++u) {
            f32x4 fx_n;
            if (u < 7) {
                const int un = u + 1;
                short8v bf_n = (short8v)0;
                if (un < 4) {
                    #pragma unroll
                    for (int q = 0; q < 4; ++q) bf_n[q] = f2bf(ELU(hacc[un][q]));
                } else {
                    #pragma unroll
                    for (int e = 0; e < 4; ++e)
                        bf_n[e] = f2bf(sfc[(g*4 + e)*64 + (((un - 4)*16 + s) ^ g8)]);
                }
                fx_n = MFMA32(a2, bf_n, z);
            }
            const float a0 = __uint_as_float(wp0[u].x << 16);
            const float a1 = __uint_as_float(wp0[u].x & 0xffff0000u);
            const float a2f = __uint_as_float(wp0[u].y << 16);
            const float a3 = __uint_as_float(wp0[u].y & 0xffff0000u);
            const float c0 = __uint_as_float(wp1[u].x << 16);
            const float c1 = __uint_as_float(wp1[u].x & 0xffff0000u);
            const float c2 = __uint_as_float(wp1[u].y << 16);
            const float c3 = __uint_as_float(wp1[u].y & 0xffff0000u);
            q0a[u] = fx_c[0]*a0 + fx_c[1]*a1 + fx_c[2]*a2f + fx_c[3]*a3;
            q1a[u] = fx_c[0]*c0 + fx_c[1]*c1 + fx_c[2]*c2 + fx_c[3]*c3;
            if (u < 7) fx_c = fx_n;
        }
        // ---- batched xor-16 ----
        #pragma unroll
        for (int u = 0; u < 8; ++u) {
            q0a[u] += __shfl_xor(q0a[u], 16);
            q1a[u] += __shfl_xor(q1a[u], 16);
        }
        // ---- xor-32 via permlane32_swap ----
        #pragma unroll
        for (int u = 0; u < 8; ++u) {
            q0a[u] = xor32_add(q0a[u]);
            q1a[u] = xor32_add(q1a[u]);
        }
        if (lane < 16) {   // g==0, s=lane
            #pragma unroll
            for (int u = 0; u < 8; ++u) {
                const int c = u*16 + s;
                const unsigned pk = packbf(q0a[u] + sbdw[2*c], q1a[u] + sbdw[2*c + 1]);
                *(unsigned*)&tmpbf[(size_t)pt*256 + 2*c] = pk;
            }
        }
    }
}

// ---------------- Kernel 3: out = elu(tmp_bf16 @ wpw^T + bpw) via MFMA ----------------
__global__ __launch_bounds__(256) void k_out(
    const unsigned short* __restrict__ tmp, const float* __restrict__ wpw,
    const float* __restrict__ bpw, float* __restrict__ out)
{
    __shared__ unsigned sb[16384];   // 64KB: [n][chunk cb^(n&7)][wi]
    const int tid = threadIdx.x;
    for (int e = tid; e < 16384; e += 256) {
        const int n = e >> 7, kw = e & 127;
        const int cb = kw >> 2, wi = kw & 3;
        const unsigned lo = (unsigned)(unsigned short)f2bf(wpw[n*256 + 2*kw]);
        const unsigned hi = (unsigned)(unsigned short)f2bf(wpw[n*256 + 2*kw + 1]);
        sb[n*128 + ((cb ^ (n & 7)) << 2) + wi] = lo | (hi << 16);
    }
    __syncthreads();

    const int lane = tid & 63, wave = tid >> 6;
    const int g = lane >> 4, s = lane & 15;
    const int row = blockIdx.x * 64 + wave * 16 + s;

    f32x4 acc[8];
    #pragma unroll
    for (int nt = 0; nt < 8; ++nt) {
        const float b = bpw[nt*16 + s];
        acc[nt][0] = b; acc[nt][1] = b; acc[nt][2] = b; acc[nt][3] = b;
    }

    const unsigned short* arow = tmp + (size_t)row * 256 + g*8;
    short8v pa = *(const short8v*)(arow);

    #pragma unroll
    for (int kk = 0; kk < 8; ++kk) {
        const short8v a = pa;
        if (kk < 7) pa = *(const short8v*)(arow + (kk+1)*32);
        #pragma unroll
        for (int nt = 0; nt < 8; ++nt) {
            const short8v bf = *(const short8v*)&sb[(nt*16 + s)*128 + (((kk*4 + g) ^ (s & 7)) << 2)];
            acc[nt] = MFMA32(a, bf, acc[nt]);
        }
    }
    const int rbase = blockIdx.x * 64 + wave * 16 + 4*g;
    #pragma unroll
    for (int nt = 0; nt < 8; ++nt)
        #pragma unroll
        for (int q = 0; q < 4; ++q)
            out[(size_t)(rbase + q) * 128 + nt*16 + s] = ELU(acc[nt][q]);
}

extern "C" void kernel_launch(void* const* d_in, const int* in_sizes, int n_in,
                              void* d_out, int out_size, void* d_ws, size_t ws_size,
                              hipStream_t stream)
{
    (void)in_sizes; (void)n_in; (void)out_size; (void)ws_size;
    const float* rep   = (const float*)d_in[0];
    const float* pts   = (const float*)d_in[1];
    const float* fts   = (const float*)d_in[2];
    const float* w1    = (const float*)d_in[3];
    const float* b1    = (const float*)d_in[4];
    const float* w2    = (const float*)d_in[5];
    const float* b2    = (const float*)d_in[6];
    const float* wconv = (const float*)d_in[7];
    const float* bconv = (const float*)d_in[8];
    const float* wdep1 = (const float*)d_in[9];
    const float* bdep1 = (const float*)d_in[10];
    const float* wdep2 = (const float*)d_in[11];
    const float* bdep2 = (const float*)d_in[12];
    const float* wdw   = (const float*)d_in[13];
    const float* bdw   = (const float*)d_in[14];
    const float* wpw   = (const float*)d_in[15];
    const float* bpw   = (const float*)d_in[16];
    float* out  = (float*)d_out;
    unsigned short* x2bf  = (unsigned short*)d_ws;                       // 16.8 MB
    unsigned short* tmpbf = (unsigned short*)((char*)d_ws + (size_t)32 * 1024 * 1024); // 16.8 MB

    hipFuncSetAttribute((const void*)k_xform, hipFuncAttributeMaxDynamicSharedMemorySize, XW_TOTAL*4);

    k_xform<<<dim3(512), dim3(256), XW_TOTAL*4, stream>>>(rep, pts, wconv, bconv, wdep1, bdep1, wdep2, bdep2, x2bf);
    k_feat <<<dim3(512), dim3(512), 0, stream>>>(rep, pts, fts, w1, b1, w2, b2, wdw, bdw, x2bf, tmpbf);
    k_out  <<<dim3(512), dim3(256), 0, stream>>>(tmpbf, wpw, bpw, out);
}

// Round 17
// 97.379 us; speedup vs baseline: 1.4710x; 1.4710x over previous
//
#include <hip/hip_runtime.h>
#include <hip/hip_bf16.h>

// XConv: N=32 P=1024 K=16 DIMS=3 C_IN=64 C_MID=64 C_OUT=128 DM=2; NP=32768
// ws layout: [0, 16.8MB) x2 bf16 ; [32MB, 48.8MB) tmp bf16. No aliasing.

#define ELU(x) ((x) > 0.0f ? (x) : (__expf(x) - 1.0f))

__device__ __forceinline__ void lds_fence() {
    asm volatile("s_waitcnt lgkmcnt(0)" ::: "memory");
}

typedef __attribute__((ext_vector_type(8))) short short8v;
typedef __attribute__((ext_vector_type(4))) float f32x4;
typedef __attribute__((ext_vector_type(2))) unsigned int uint2v;
#define MFMA32(a, b, c) __builtin_amdgcn_mfma_f32_16x16x32_bf16(a, b, c, 0, 0, 0)

__device__ __forceinline__ short f2bf(float x) {
    __hip_bfloat16 h = __float2bfloat16(x);
    return *reinterpret_cast<short*>(&h);
}
__device__ __forceinline__ float bf2f(short x) {
    unsigned u = ((unsigned)(unsigned short)x) << 16;
    return __uint_as_float(u);
}
__device__ __forceinline__ unsigned packbf(float a, float b) {
    return (unsigned)(unsigned short)f2bf(a) | (((unsigned)(unsigned short)f2bf(b)) << 16);
}
__device__ __forceinline__ void gload_lds16(const float* g, float* l) {
    __builtin_amdgcn_global_load_lds(
        (const __attribute__((address_space(1))) void*)g,
        (__attribute__((address_space(3))) void*)l,
        16, 0, 0);
}
// full xor-32 exchange+add, pure VALU
__device__ __forceinline__ float xor32_add(float q) {
    uint2v r = __builtin_amdgcn_permlane32_swap(__float_as_uint(q), __float_as_uint(q), false, false);
    return __uint_as_float(r.x) + __uint_as_float(r.y);
}

// ---------------- Kernel 1: X-transform via MFMA (bf16 X2 output) ----------------
#define XW_WC   0        // bf16 frag entries: idx=(part*16+u)*64+lane, 16B each (8192 words)
#define XW_WD1  8192     // wdep1: i*260 + j*16 + k  (4160 words)
#define XW_WD2  12352    // wdep2 same               (4160)
#define XW_BC   16512    // bconv 256
#define XW_BD1  16768    // 256
#define XW_BD2  17024    // 256
#define XW_SCR  17280    // + wave*4368 : per-point stride 273, scr[p*273 + j*17 + s]
#define XW_TOTAL (17280 + 4*4368)   // 34752 words = 139008 B

__global__ __launch_bounds__(256) void k_xform(
    const float* __restrict__ rep, const float* __restrict__ pts,
    const float* __restrict__ wconv, const float* __restrict__ bconv,
    const float* __restrict__ wdep1, const float* __restrict__ bdep1,
    const float* __restrict__ wdep2, const float* __restrict__ bdep2,
    unsigned short* __restrict__ x2bf)
{
    extern __shared__ __align__(16) float sm[];
    short* smh = (short*)sm;
    const int tid = threadIdx.x;

    for (int e = tid; e < 2048; e += 256) {
        const int part = e >> 10, u = (e >> 6) & 15, l = e & 63;
        const int g = l >> 4, s = l & 15;
        const int o = u * 16 + s;
        short8v v;
        if (part == 0) {
            #pragma unroll
            for (int t = 0; t < 8; ++t) v[t] = f2bf(wconv[o*48 + g*8 + t]);
        } else {
            #pragma unroll
            for (int t = 0; t < 4; ++t) v[t] = f2bf(wconv[o*48 + 32 + g*4 + t]);
            #pragma unroll
            for (int t = 4; t < 8; ++t) v[t] = 0;
        }
        *(short8v*)&smh[e * 8] = v;
    }
    for (int e = tid; e < 4096; e += 256) {
        const int i = e >> 8, j = (e >> 4) & 15, k = e & 15;
        sm[XW_WD1 + i*260 + j*16 + k] = wdep1[e];
        sm[XW_WD2 + i*260 + j*16 + k] = wdep2[e];
    }
    sm[XW_BC  + tid] = bconv[tid];
    sm[XW_BD1 + tid] = bdep1[tid];
    sm[XW_BD2 + tid] = bdep2[tid];
    __syncthreads();

    const int wave = tid >> 6, lane = tid & 63;
    const int g = lane >> 4, s = lane & 15;
    const int pt0 = (blockIdx.x * 4 + wave) * 16;

    const int p = pt0 + s;
    const float r0 = rep[p*3], r1 = rep[p*3+1], r2 = rep[p*3+2];
    short8v ah0, al0, ah1, al1;
    #pragma unroll
    for (int e = 0; e < 8; ++e) {
        const int r = g*8 + e;
        const int d = g >> 1, k = r & 15;
        const float v = pts[p*48 + k*3 + d] - (d == 0 ? r0 : r1);
        const short h = f2bf(v);
        ah0[e] = h; al0[e] = f2bf(v - bf2f(h));
    }
    #pragma unroll
    for (int e = 0; e < 4; ++e) {
        const int k = g*4 + e;
        const float v = pts[p*48 + k*3 + 2] - r2;
        const short h = f2bf(v);
        ah1[e] = h; al1[e] = f2bf(v - bf2f(h));
    }
    #pragma unroll
    for (int e = 4; e < 8; ++e) { ah1[e] = 0; al1[e] = 0; }

    f32x4 ex[16];
    #pragma unroll
    for (int u = 0; u < 16; ++u) {
        const float b = sm[XW_BC + u*16 + s];
        f32x4 acc; acc[0] = b; acc[1] = b; acc[2] = b; acc[3] = b;
        const short8v bh0 = *(const short8v*)&smh[(u*64 + lane) * 8];
        const short8v bh1 = *(const short8v*)&smh[((16 + u)*64 + lane) * 8];
        acc = MFMA32(ah0, bh0, acc);
        acc = MFMA32(ah1, bh1, acc);
        acc = MFMA32(al0, bh0, acc);
        acc = MFMA32(al1, bh1, acc);
        f32x4 r;
        r[0] = ELU(acc[0]); r[1] = ELU(acc[1]); r[2] = ELU(acc[2]); r[3] = ELU(acc[3]);
        ex[u] = r;
    }

    const int scrb = XW_SCR + wave * 4368;
    #pragma unroll
    for (int j = 0; j < 16; ++j) {
        const float b = sm[XW_BD1 + s*16 + j];
        f32x4 a; a[0] = b; a[1] = b; a[2] = b; a[3] = b;
        #pragma unroll
        for (int kb = 0; kb < 4; ++kb) {
            const float4 w = *(const float4*)&sm[XW_WD1 + s*260 + j*16 + kb*4];
            a += ex[kb*4+0] * w.x; a += ex[kb*4+1] * w.y;
            a += ex[kb*4+2] * w.z; a += ex[kb*4+3] * w.w;
        }
        #pragma unroll
        for (int q = 0; q < 4; ++q)
            sm[scrb + (g*4+q)*273 + j*17 + s] = ELU(a[q]);
    }
    lds_fence();

    f32x4 xr[16];
    #pragma unroll
    for (int k = 0; k < 16; ++k) {
        f32x4 v;
        #pragma unroll
        for (int q = 0; q < 4; ++q)
            v[q] = sm[scrb + (g*4+q)*273 + s*17 + k];
        xr[k] = v;
    }
    f32x4 oj[16];
    #pragma unroll
    for (int j = 0; j < 16; ++j) {
        const float b = sm[XW_BD2 + s*16 + j];
        f32x4 a; a[0] = b; a[1] = b; a[2] = b; a[3] = b;
        #pragma unroll
        for (int kb = 0; kb < 4; ++kb) {
            const float4 w = *(const float4*)&sm[XW_WD2 + s*260 + j*16 + kb*4];
            a += xr[kb*4+0] * w.x; a += xr[kb*4+1] * w.y;
            a += xr[kb*4+2] * w.z; a += xr[kb*4+3] * w.w;
        }
        oj[j] = a;
    }
    #pragma unroll
    for (int q = 0; q < 4; ++q) {
        const int pp = pt0 + g*4 + q;
        #pragma unroll
        for (int jb = 0; jb < 4; ++jb) {
            uint2 pk;
            pk.x = packbf(oj[jb*4+0][q], oj[jb*4+1][q]);
            pk.y = packbf(oj[jb*4+2][q], oj[jb*4+3][q]);
            *(uint2*)&x2bf[(size_t)pp*256 + s*16 + jb*4] = pk;
        }
    }
}

// ---------------- Kernel 2: MFMA features; PAIR-ILP (2 points/iter, 2 chains/wave) ----
// (256,3) reg tier (R16 proved 128-cap spills). LDS 73.7KB -> 2 blocks/CU = 8 waves/CU;
// 2 waves/SIMD x 2 independent chains = 4 chains/SIMD (vs 3). Per-iter fence cost halves.
// vmcnt(24): queue at fence = prevDMA(8)+prevScalars(14)+prevStores(16)+freshDMA(8);
// waiting to 24 retires exactly prevDMA+prevScalars, keeps stores+fresh in flight.
#define NPAIRS 16384
#define TOTWP 2048
__global__ __launch_bounds__(256, 3) void k_feat(
    const float* __restrict__ rep, const float* __restrict__ pts, const float* __restrict__ fts,
    const float* __restrict__ w1, const float* __restrict__ b1,
    const float* __restrict__ w2, const float* __restrict__ b2,
    const float* __restrict__ wdw, const float* __restrict__ bdw,
    const unsigned short* __restrict__ x2bf, unsigned short* __restrict__ tmpbf)
{
    __shared__ __align__(16) short sw2[4096];      // B-frags: rec r=nt*2+h, 16B @ (r*64+lane)
    __shared__ __align__(16) uint2 sw1[64];        // j: {pack(w1[0][j],w1[1][j]), pack(w1[2][j],b1[j])}
    __shared__ float sbdw[256];
    __shared__ __align__(16) float sfts[4][2][2048]; // [wave][buf][2-point fts tile] 64KB
    const int tid = threadIdx.x;

    for (int idx = tid; idx < 512; idx += 256) {   // 512 recs of 8 bf16
        const int r = idx >> 6, l = idx & 63;
        const int nt = r >> 1, h = r & 1, gg = l >> 4, ss = l & 15;
        short8v v;
        #pragma unroll
        for (int e = 0; e < 8; ++e)
            v[e] = f2bf(w2[(h*32 + gg*8 + e)*64 + nt*16 + ss]);
        *(short8v*)&sw2[idx * 8] = v;
    }
    if (tid < 64) {
        const int j = tid;
        uint2 v;
        v.x = packbf(w1[j], w1[64 + j]);
        v.y = packbf(w1[128 + j], b1[j]);
        sw1[j] = v;
    }
    sbdw[tid] = bdw[tid];
    __syncthreads();

    const int lane = tid & 63, wave = tid >> 6;
    const int g = lane >> 4, s = lane & 15;
    const int g8 = g * 8;

    float b2c[4];
    #pragma unroll
    for (int nt = 0; nt < 4; ++nt) b2c[nt] = b2[nt*16 + s];

    // ---- wdw -> per-lane regs (bf16 pairs), loop-invariant ----
    uint2 wp0[8], wp1[8];
    #pragma unroll
    for (int u = 0; u < 8; ++u) {
        const int cb = (u*16 + s) * 32 + 4*g;
        wp0[u].x = packbf(wdw[cb + 0],  wdw[cb + 1]);
        wp0[u].y = packbf(wdw[cb + 2],  wdw[cb + 3]);
        wp1[u].x = packbf(wdw[cb + 16], wdw[cb + 17]);
        wp1[u].y = packbf(wdw[cb + 18], wdw[cb + 19]);
    }

    const int pw = blockIdx.x * 4 + wave;   // pair-wave id 0..2047
    float* sf0 = &sfts[wave][0][0];
    float* sf1 = &sfts[wave][1][0];

    // ---- prologue: DMA pair pw (2 points, 8 chunks); prefetch scalars for both points ----
    {
        const float* base = fts + (size_t)(2*pw) * 1024;
        #pragma unroll
        for (int a = 0; a < 2; ++a)
            #pragma unroll
            for (int i = 0; i < 4; ++i)
                gload_lds16(base + a*1024 + i*256 + (lane ^ (2*i))*4, sf0 + a*1024 + i*256);
    }
    ushort4 xvn0, xvn1; float pn0[3], pn1[3];
    {
        const int pt0i = 2*pw, pt1i = 2*pw + 1;
        xvn0 = *(const ushort4*)&x2bf[(size_t)pt0i*256 + s*16 + g*4];
        xvn1 = *(const ushort4*)&x2bf[(size_t)pt1i*256 + s*16 + g*4];
        pn0[0] = pts[pt0i*48 + s*3 + 0] - rep[pt0i*3 + 0];
        pn0[1] = pts[pt0i*48 + s*3 + 1] - rep[pt0i*3 + 1];
        pn0[2] = pts[pt0i*48 + s*3 + 2] - rep[pt0i*3 + 2];
        pn1[0] = pts[pt1i*48 + s*3 + 0] - rep[pt1i*3 + 0];
        pn1[1] = pts[pt1i*48 + s*3 + 1] - rep[pt1i*3 + 1];
        pn1[2] = pts[pt1i*48 + s*3 + 2] - rep[pt1i*3 + 2];
    }

    int k = 0;
    for (int pr = pw; pr < NPAIRS; pr += TOTWP, ++k) {
        float* sfc = (k & 1) ? sf1 : sf0;
        float* sfn = (k & 1) ? sf0 : sf1;
        const int prn = pr + TOTWP;

        // ---- step 1: issue DMA(next pair) ----
        if (prn < NPAIRS) {
            const float* base = fts + (size_t)(2*prn) * 1024;
            #pragma unroll
            for (int a = 0; a < 2; ++a)
                #pragma unroll
                for (int i = 0; i < 4; ++i)
                    gload_lds16(base + a*1024 + i*256 + (lane ^ (2*i))*4, sfn + a*1024 + i*256);
        }
        // ---- step 2: counted wait: retires prev DMA(+prev scalars), keeps stores+fresh ----
        asm volatile("s_waitcnt vmcnt(24)" ::: "memory");

        const ushort4 xv0 = xvn0, xv1 = xvn1;
        const float p00 = pn0[0], p01 = pn0[1], p02 = pn0[2];
        const float p10 = pn1[0], p11 = pn1[1], p12 = pn1[2];

        // ---- step 3: scalar prefetch(next pair) ----
        if (prn < NPAIRS) {
            const int n0 = 2*prn, n1 = 2*prn + 1;
            xvn0 = *(const ushort4*)&x2bf[(size_t)n0*256 + s*16 + g*4];
            xvn1 = *(const ushort4*)&x2bf[(size_t)n1*256 + s*16 + g*4];
            pn0[0] = pts[n0*48 + s*3 + 0] - rep[n0*3 + 0];
            pn0[1] = pts[n0*48 + s*3 + 1] - rep[n0*3 + 1];
            pn0[2] = pts[n0*48 + s*3 + 2] - rep[n0*3 + 2];
            pn1[0] = pts[n1*48 + s*3 + 0] - rep[n1*3 + 0];
            pn1[1] = pts[n1*48 + s*3 + 1] - rep[n1*3 + 1];
            pn1[2] = pts[n1*48 + s*3 + 2] - rep[n1*3 + 2];
        }

        // ---- phase A: h1+h2 for BOTH points (two independent chains) ----
        f32x4 hacc0[4], hacc1[4];
        {
            short8v af00, af01, af10, af11;
            #pragma unroll
            for (int t = 0; t < 2; ++t) {
                short8v f0, f1;
                #pragma unroll
                for (int e = 0; e < 8; ++e) {
                    const uint2 pk = sw1[t*32 + g*8 + e];
                    const float wx = __uint_as_float(pk.x << 16);
                    const float wy = __uint_as_float(pk.x & 0xffff0000u);
                    const float wz = __uint_as_float(pk.y << 16);
                    const float bb = __uint_as_float(pk.y & 0xffff0000u);
                    float h0 = bb + p00*wx + p01*wy + p02*wz;
                    float h1 = bb + p10*wx + p11*wy + p12*wz;
                    h0 = ELU(h0); h1 = ELU(h1);
                    f0[e] = f2bf(h0); f1[e] = f2bf(h1);
                }
                if (t == 0) { af00 = f0; af10 = f1; } else { af01 = f0; af11 = f1; }
            }
            #pragma unroll
            for (int nt = 0; nt < 4; ++nt) {
                f32x4 a0, a1;
                a0[0] = b2c[nt]; a0[1] = b2c[nt]; a0[2] = b2c[nt]; a0[3] = b2c[nt];
                a1 = a0;
                const short8v bf0 = *(const short8v*)&sw2[((nt*2 + 0)*64 + lane) * 8];
                const short8v bf1 = *(const short8v*)&sw2[((nt*2 + 1)*64 + lane) * 8];
                a0 = MFMA32(af00, bf0, a0); a0 = MFMA32(af01, bf1, a0);
                a1 = MFMA32(af10, bf0, a1); a1 = MFMA32(af11, bf1, a1);
                hacc0[nt] = a0; hacc1[nt] = a1;
            }
        }
        short8v a20 = (short8v)0, a21 = (short8v)0;
        a20[0] = (short)xv0.x; a20[1] = (short)xv0.y; a20[2] = (short)xv0.z; a20[3] = (short)xv0.w;
        a21[0] = (short)xv1.x; a21[1] = (short)xv1.y; a21[2] = (short)xv1.z; a21[3] = (short)xv1.w;

        // ---- phase B: both points per u-tile (chains interleave) ----
        f32x4 z; z[0] = 0.f; z[1] = 0.f; z[2] = 0.f; z[3] = 0.f;
        float q00[8], q01[8], q10[8], q11[8];
        #pragma unroll
        for (int u = 0; u < 8; ++u) {
            short8v bfr0 = (short8v)0, bfr1 = (short8v)0;
            if (u < 4) {
                #pragma unroll
                for (int q = 0; q < 4; ++q) { bfr0[q] = f2bf(ELU(hacc0[u][q])); bfr1[q] = f2bf(ELU(hacc1[u][q])); }
            } else {
                #pragma unroll
                for (int e = 0; e < 4; ++e) {
                    const int off = (g*4 + e)*64 + ((((u - 4)*16 + s)) ^ g8);
                    bfr0[e] = f2bf(sfc[off]);
                    bfr1[e] = f2bf(sfc[1024 + off]);
                }
            }
            const f32x4 fx0 = MFMA32(a20, bfr0, z);
            const f32x4 fx1 = MFMA32(a21, bfr1, z);

            const float a0 = __uint_as_float(wp0[u].x << 16);
            const float a1 = __uint_as_float(wp0[u].x & 0xffff0000u);
            const float a2f = __uint_as_float(wp0[u].y << 16);
            const float a3 = __uint_as_float(wp0[u].y & 0xffff0000u);
            const float c0 = __uint_as_float(wp1[u].x << 16);
            const float c1 = __uint_as_float(wp1[u].x & 0xffff0000u);
            const float c2 = __uint_as_float(wp1[u].y << 16);
            const float c3 = __uint_as_float(wp1[u].y & 0xffff0000u);
            q00[u] = fx0[0]*a0 + fx0[1]*a1 + fx0[2]*a2f + fx0[3]*a3;
            q01[u] = fx0[0]*c0 + fx0[1]*c1 + fx0[2]*c2 + fx0[3]*c3;
            q10[u] = fx1[0]*a0 + fx1[1]*a1 + fx1[2]*a2f + fx1[3]*a3;
            q11[u] = fx1[0]*c0 + fx1[1]*c1 + fx1[2]*c2 + fx1[3]*c3;
        }
        // ---- batched xor-16 (32 independent swizzles overlap) ----
        #pragma unroll
        for (int u = 0; u < 8; ++u) {
            q00[u] += __shfl_xor(q00[u], 16);
            q01[u] += __shfl_xor(q01[u], 16);
            q10[u] += __shfl_xor(q10[u], 16);
            q11[u] += __shfl_xor(q11[u], 16);
        }
        // ---- xor-32 via permlane32_swap (pure VALU) ----
        #pragma unroll
        for (int u = 0; u < 8; ++u) {
            q00[u] = xor32_add(q00[u]);
            q01[u] = xor32_add(q01[u]);
            q10[u] = xor32_add(q10[u]);
            q11[u] = xor32_add(q11[u]);
        }
        if (lane < 16) {   // g==0, s=lane
            const size_t b0 = (size_t)(2*pr) * 256, b1 = (size_t)(2*pr + 1) * 256;
            #pragma unroll
            for (int u = 0; u < 8; ++u) {
                const int c = u*16 + s;
                *(unsigned*)&tmpbf[b0 + 2*c] = packbf(q00[u] + sbdw[2*c], q01[u] + sbdw[2*c + 1]);
                *(unsigned*)&tmpbf[b1 + 2*c] = packbf(q10[u] + sbdw[2*c], q11[u] + sbdw[2*c + 1]);
            }
        }
    }
}

// ---------------- Kernel 3: out = elu(tmp_bf16 @ wpw^T + bpw) via MFMA ----------------
__global__ __launch_bounds__(256) void k_out(
    const unsigned short* __restrict__ tmp, const float* __restrict__ wpw,
    const float* __restrict__ bpw, float* __restrict__ out)
{
    __shared__ unsigned sb[16384];   // 64KB: [n][chunk cb^(n&7)][wi]
    const int tid = threadIdx.x;
    for (int e = tid; e < 16384; e += 256) {
        const int n = e >> 7, kw = e & 127;
        const int cb = kw >> 2, wi = kw & 3;
        const unsigned lo = (unsigned)(unsigned short)f2bf(wpw[n*256 + 2*kw]);
        const unsigned hi = (unsigned)(unsigned short)f2bf(wpw[n*256 + 2*kw + 1]);
        sb[n*128 + ((cb ^ (n & 7)) << 2) + wi] = lo | (hi << 16);
    }
    __syncthreads();

    const int lane = tid & 63, wave = tid >> 6;
    const int g = lane >> 4, s = lane & 15;
    const int row = blockIdx.x * 64 + wave * 16 + s;

    f32x4 acc[8];
    #pragma unroll
    for (int nt = 0; nt < 8; ++nt) {
        const float b = bpw[nt*16 + s];
        acc[nt][0] = b; acc[nt][1] = b; acc[nt][2] = b; acc[nt][3] = b;
    }

    const unsigned short* arow = tmp + (size_t)row * 256 + g*8;
    short8v pa = *(const short8v*)(arow);

    #pragma unroll
    for (int kk = 0; kk < 8; ++kk) {
        const short8v a = pa;
        if (kk < 7) pa = *(const short8v*)(arow + (kk+1)*32);
        #pragma unroll
        for (int nt = 0; nt < 8; ++nt) {
            const short8v bf = *(const short8v*)&sb[(nt*16 + s)*128 + (((kk*4 + g) ^ (s & 7)) << 2)];
            acc[nt] = MFMA32(a, bf, acc[nt]);
        }
    }
    const int rbase = blockIdx.x * 64 + wave * 16 + 4*g;
    #pragma unroll
    for (int nt = 0; nt < 8; ++nt)
        #pragma unroll
        for (int q = 0; q < 4; ++q)
            out[(size_t)(rbase + q) * 128 + nt*16 + s] = ELU(acc[nt][q]);
}

extern "C" void kernel_launch(void* const* d_in, const int* in_sizes, int n_in,
                              void* d_out, int out_size, void* d_ws, size_t ws_size,
                              hipStream_t stream)
{
    (void)in_sizes; (void)n_in; (void)out_size; (void)ws_size;
    const float* rep   = (const float*)d_in[0];
    const float* pts   = (const float*)d_in[1];
    const float* fts   = (const float*)d_in[2];
    const float* w1    = (const float*)d_in[3];
    const float* b1    = (const float*)d_in[4];
    const float* w2    = (const float*)d_in[5];
    const float* b2    = (const float*)d_in[6];
    const float* wconv = (const float*)d_in[7];
    const float* bconv = (const float*)d_in[8];
    const float* wdep1 = (const float*)d_in[9];
    const float* bdep1 = (const float*)d_in[10];
    const float* wdep2 = (const float*)d_in[11];
    const float* bdep2 = (const float*)d_in[12];
    const float* wdw   = (const float*)d_in[13];
    const float* bdw   = (const float*)d_in[14];
    const float* wpw   = (const float*)d_in[15];
    const float* bpw   = (const float*)d_in[16];
    float* out  = (float*)d_out;
    unsigned short* x2bf  = (unsigned short*)d_ws;                       // 16.8 MB
    unsigned short* tmpbf = (unsigned short*)((char*)d_ws + (size_t)32 * 1024 * 1024); // 16.8 MB

    hipFuncSetAttribute((const void*)k_xform, hipFuncAttributeMaxDynamicSharedMemorySize, XW_TOTAL*4);

    k_xform<<<dim3(512), dim3(256), XW_TOTAL*4, stream>>>(rep, pts, wconv, bconv, wdep1, bdep1, wdep2, bdep2, x2bf);
    k_feat <<<dim3(512), dim3(256), 0, stream>>>(rep, pts, fts, w1, b1, w2, b2, wdw, bdw, x2bf, tmpbf);
    k_out  <<<dim3(512), dim3(256), 0, stream>>>(tmpbf, wpw, bpw, out);
}

// Round 18
// 93.932 us; speedup vs baseline: 1.5250x; 1.0367x over previous
//
#include <hip/hip_runtime.h>
#include <hip/hip_bf16.h>

// XConv: N=32 P=1024 K=16 DIMS=3 C_IN=64 C_MID=64 C_OUT=128 DM=2; NP=32768
// ws layout: [0, 16.8MB) x2 bf16 ; [32MB, 48.8MB) tmp bf16. No aliasing.
// R18 = revert to R15 (best measured: 93.8us). R16 (16-wave) and R17 (pair-ILP) both regressed.

#define ELU(x) ((x) > 0.0f ? (x) : (__expf(x) - 1.0f))

__device__ __forceinline__ void lds_fence() {
    asm volatile("s_waitcnt lgkmcnt(0)" ::: "memory");
}

typedef __attribute__((ext_vector_type(8))) short short8v;
typedef __attribute__((ext_vector_type(4))) float f32x4;
typedef __attribute__((ext_vector_type(2))) unsigned int uint2v;
#define MFMA32(a, b, c) __builtin_amdgcn_mfma_f32_16x16x32_bf16(a, b, c, 0, 0, 0)

__device__ __forceinline__ short f2bf(float x) {
    __hip_bfloat16 h = __float2bfloat16(x);
    return *reinterpret_cast<short*>(&h);
}
__device__ __forceinline__ float bf2f(short x) {
    unsigned u = ((unsigned)(unsigned short)x) << 16;
    return __uint_as_float(u);
}
__device__ __forceinline__ unsigned packbf(float a, float b) {
    return (unsigned)(unsigned short)f2bf(a) | (((unsigned)(unsigned short)f2bf(b)) << 16);
}
__device__ __forceinline__ void gload_lds16(const float* g, float* l) {
    __builtin_amdgcn_global_load_lds(
        (const __attribute__((address_space(1))) void*)g,
        (__attribute__((address_space(3))) void*)l,
        16, 0, 0);
}
// full xor-32 exchange+add, pure VALU
__device__ __forceinline__ float xor32_add(float q) {
    uint2v r = __builtin_amdgcn_permlane32_swap(__float_as_uint(q), __float_as_uint(q), false, false);
    return __uint_as_float(r.x) + __uint_as_float(r.y);
}

// ---------------- Kernel 1: X-transform via MFMA (bf16 X2 output) ----------------
#define XW_WC   0        // bf16 frag entries: idx=(part*16+u)*64+lane, 16B each (8192 words)
#define XW_WD1  8192     // wdep1: i*260 + j*16 + k  (4160 words)
#define XW_WD2  12352    // wdep2 same               (4160)
#define XW_BC   16512    // bconv 256
#define XW_BD1  16768    // 256
#define XW_BD2  17024    // 256
#define XW_SCR  17280    // + wave*4368 : per-point stride 273, scr[p*273 + j*17 + s]
#define XW_TOTAL (17280 + 4*4368)   // 34752 words = 139008 B

__global__ __launch_bounds__(256) void k_xform(
    const float* __restrict__ rep, const float* __restrict__ pts,
    const float* __restrict__ wconv, const float* __restrict__ bconv,
    const float* __restrict__ wdep1, const float* __restrict__ bdep1,
    const float* __restrict__ wdep2, const float* __restrict__ bdep2,
    unsigned short* __restrict__ x2bf)
{
    extern __shared__ __align__(16) float sm[];
    short* smh = (short*)sm;
    const int tid = threadIdx.x;

    for (int e = tid; e < 2048; e += 256) {
        const int part = e >> 10, u = (e >> 6) & 15, l = e & 63;
        const int g = l >> 4, s = l & 15;
        const int o = u * 16 + s;
        short8v v;
        if (part == 0) {
            #pragma unroll
            for (int t = 0; t < 8; ++t) v[t] = f2bf(wconv[o*48 + g*8 + t]);
        } else {
            #pragma unroll
            for (int t = 0; t < 4; ++t) v[t] = f2bf(wconv[o*48 + 32 + g*4 + t]);
            #pragma unroll
            for (int t = 4; t < 8; ++t) v[t] = 0;
        }
        *(short8v*)&smh[e * 8] = v;
    }
    for (int e = tid; e < 4096; e += 256) {
        const int i = e >> 8, j = (e >> 4) & 15, k = e & 15;
        sm[XW_WD1 + i*260 + j*16 + k] = wdep1[e];
        sm[XW_WD2 + i*260 + j*16 + k] = wdep2[e];
    }
    sm[XW_BC  + tid] = bconv[tid];
    sm[XW_BD1 + tid] = bdep1[tid];
    sm[XW_BD2 + tid] = bdep2[tid];
    __syncthreads();

    const int wave = tid >> 6, lane = tid & 63;
    const int g = lane >> 4, s = lane & 15;
    const int pt0 = (blockIdx.x * 4 + wave) * 16;

    const int p = pt0 + s;
    const float r0 = rep[p*3], r1 = rep[p*3+1], r2 = rep[p*3+2];
    short8v ah0, al0, ah1, al1;
    #pragma unroll
    for (int e = 0; e < 8; ++e) {
        const int r = g*8 + e;
        const int d = g >> 1, k = r & 15;
        const float v = pts[p*48 + k*3 + d] - (d == 0 ? r0 : r1);
        const short h = f2bf(v);
        ah0[e] = h; al0[e] = f2bf(v - bf2f(h));
    }
    #pragma unroll
    for (int e = 0; e < 4; ++e) {
        const int k = g*4 + e;
        const float v = pts[p*48 + k*3 + 2] - r2;
        const short h = f2bf(v);
        ah1[e] = h; al1[e] = f2bf(v - bf2f(h));
    }
    #pragma unroll
    for (int e = 4; e < 8; ++e) { ah1[e] = 0; al1[e] = 0; }

    f32x4 ex[16];
    #pragma unroll
    for (int u = 0; u < 16; ++u) {
        const float b = sm[XW_BC + u*16 + s];
        f32x4 acc; acc[0] = b; acc[1] = b; acc[2] = b; acc[3] = b;
        const short8v bh0 = *(const short8v*)&smh[(u*64 + lane) * 8];
        const short8v bh1 = *(const short8v*)&smh[((16 + u)*64 + lane) * 8];
        acc = MFMA32(ah0, bh0, acc);
        acc = MFMA32(ah1, bh1, acc);
        acc = MFMA32(al0, bh0, acc);
        acc = MFMA32(al1, bh1, acc);
        f32x4 r;
        r[0] = ELU(acc[0]); r[1] = ELU(acc[1]); r[2] = ELU(acc[2]); r[3] = ELU(acc[3]);
        ex[u] = r;
    }

    const int scrb = XW_SCR + wave * 4368;
    #pragma unroll
    for (int j = 0; j < 16; ++j) {
        const float b = sm[XW_BD1 + s*16 + j];
        f32x4 a; a[0] = b; a[1] = b; a[2] = b; a[3] = b;
        #pragma unroll
        for (int kb = 0; kb < 4; ++kb) {
            const float4 w = *(const float4*)&sm[XW_WD1 + s*260 + j*16 + kb*4];
            a += ex[kb*4+0] * w.x; a += ex[kb*4+1] * w.y;
            a += ex[kb*4+2] * w.z; a += ex[kb*4+3] * w.w;
        }
        #pragma unroll
        for (int q = 0; q < 4; ++q)
            sm[scrb + (g*4+q)*273 + j*17 + s] = ELU(a[q]);
    }
    lds_fence();

    f32x4 xr[16];
    #pragma unroll
    for (int k = 0; k < 16; ++k) {
        f32x4 v;
        #pragma unroll
        for (int q = 0; q < 4; ++q)
            v[q] = sm[scrb + (g*4+q)*273 + s*17 + k];
        xr[k] = v;
    }
    f32x4 oj[16];
    #pragma unroll
    for (int j = 0; j < 16; ++j) {
        const float b = sm[XW_BD2 + s*16 + j];
        f32x4 a; a[0] = b; a[1] = b; a[2] = b; a[3] = b;
        #pragma unroll
        for (int kb = 0; kb < 4; ++kb) {
            const float4 w = *(const float4*)&sm[XW_WD2 + s*260 + j*16 + kb*4];
            a += xr[kb*4+0] * w.x; a += xr[kb*4+1] * w.y;
            a += xr[kb*4+2] * w.z; a += xr[kb*4+3] * w.w;
        }
        oj[j] = a;
    }
    #pragma unroll
    for (int q = 0; q < 4; ++q) {
        const int pp = pt0 + g*4 + q;
        #pragma unroll
        for (int jb = 0; jb < 4; ++jb) {
            uint2 pk;
            pk.x = packbf(oj[jb*4+0][q], oj[jb*4+1][q]);
            pk.y = packbf(oj[jb*4+2][q], oj[jb*4+3][q]);
            *(uint2*)&x2bf[(size_t)pp*256 + s*16 + jb*4] = pk;
        }
    }
}

// ---------------- Kernel 2: MFMA features (R15 config: best measured) ----------
// (256,3) tier, grid 768 (3 blocks/CU resident), dbuf swizzled DMA, counted vmcnt(11),
// reg wdw, batched xor16 + permlane32 reduce, software-pipelined phase B.
#define NPTS 32768
#define TOTW 3072
__global__ __launch_bounds__(256, 3) void k_feat(
    const float* __restrict__ rep, const float* __restrict__ pts, const float* __restrict__ fts,
    const float* __restrict__ w1, const float* __restrict__ b1,
    const float* __restrict__ w2, const float* __restrict__ b2,
    const float* __restrict__ wdw, const float* __restrict__ bdw,
    const unsigned short* __restrict__ x2bf, unsigned short* __restrict__ tmpbf)
{
    __shared__ __align__(16) short sw2[4096];      // B-frags: rec r=nt*2+h, 16B @ (r*64+lane)
    __shared__ __align__(16) uint2 sw1[64];        // j: {pack(w1[0][j],w1[1][j]), pack(w1[2][j],b1[j])}
    __shared__ float sbdw[256];
    __shared__ __align__(16) float sfts[4][2][1024]; // [wave][buf][fts tile, sigma-swizzled]
    const int tid = threadIdx.x;

    for (int idx = tid; idx < 512; idx += 256) {   // 512 recs of 8 bf16
        const int r = idx >> 6, l = idx & 63;
        const int nt = r >> 1, h = r & 1, gg = l >> 4, ss = l & 15;
        short8v v;
        #pragma unroll
        for (int e = 0; e < 8; ++e)
            v[e] = f2bf(w2[(h*32 + gg*8 + e)*64 + nt*16 + ss]);
        *(short8v*)&sw2[idx * 8] = v;
    }
    if (tid < 64) {
        const int j = tid;
        uint2 v;
        v.x = packbf(w1[j], w1[64 + j]);
        v.y = packbf(w1[128 + j], b1[j]);
        sw1[j] = v;
    }
    sbdw[tid] = bdw[tid];
    __syncthreads();

    const int lane = tid & 63, wave = tid >> 6;
    const int g = lane >> 4, s = lane & 15;
    const int g8 = g * 8;

    float b2c[4];
    #pragma unroll
    for (int nt = 0; nt < 4; ++nt) b2c[nt] = b2[nt*16 + s];

    // ---- wdw -> per-lane regs (bf16 pairs), loop-invariant ----
    uint2 wp0[8], wp1[8];
    #pragma unroll
    for (int u = 0; u < 8; ++u) {
        const int cb = (u*16 + s) * 32 + 4*g;
        wp0[u].x = packbf(wdw[cb + 0],  wdw[cb + 1]);
        wp0[u].y = packbf(wdw[cb + 2],  wdw[cb + 3]);
        wp1[u].x = packbf(wdw[cb + 16], wdw[cb + 17]);
        wp1[u].y = packbf(wdw[cb + 18], wdw[cb + 19]);
    }

    const int gw = blockIdx.x * 4 + wave;   // 0..3071
    float* sf0 = &sfts[wave][0][0];
    float* sf1 = &sfts[wave][1][0];

    // ---- prologue: swizzled DMA pt=gw into buf0; prefetch scalars(gw) ----
    {
        const float* base = fts + (size_t)gw * 1024;
        #pragma unroll
        for (int i = 0; i < 4; ++i)
            gload_lds16(base + i*256 + (lane ^ (2*i))*4, sf0 + i*256);
    }
    ushort4 xv_n = *(const ushort4*)&x2bf[(size_t)gw*256 + s*16 + g*4];
    float p0_n = pts[gw*48 + s*3 + 0] - rep[gw*3 + 0];
    float p1_n = pts[gw*48 + s*3 + 1] - rep[gw*3 + 1];
    float p2_n = pts[gw*48 + s*3 + 2] - rep[gw*3 + 2];

    int k = 0;
    for (int pt = gw; pt < NPTS; pt += TOTW, ++k) {
        float* sfc = (k & 1) ? sf1 : sf0;
        float* sfn = (k & 1) ? sf0 : sf1;
        const int ptn = pt + TOTW;

        // ---- step 1: issue swizzled DMA(ptn) ----
        if (ptn < NPTS) {
            const float* base = fts + (size_t)ptn * 1024;
            #pragma unroll
            for (int i = 0; i < 4; ++i)
                gload_lds16(base + i*256 + (lane ^ (2*i))*4, sfn + i*256);
        }
        // ---- step 2: counted wait — retires DMA(pt)+scalars(pt), not stores/fresh ----
        asm volatile("s_waitcnt vmcnt(11)" ::: "memory");

        const ushort4 xv = xv_n;
        const float p0 = p0_n, p1 = p1_n, p2 = p2_n;

        // ---- step 3: scalar prefetch(ptn) ----
        if (ptn < NPTS) {
            xv_n = *(const ushort4*)&x2bf[(size_t)ptn*256 + s*16 + g*4];
            p0_n = pts[ptn*48 + s*3 + 0] - rep[ptn*3 + 0];
            p1_n = pts[ptn*48 + s*3 + 1] - rep[ptn*3 + 1];
            p2_n = pts[ptn*48 + s*3 + 2] - rep[ptn*3 + 2];
        }

        // ---- phase A: h1 in A-frag layout; h2 via 8 MFMA ----
        short8v af0, af1;
        #pragma unroll
        for (int t = 0; t < 2; ++t) {
            short8v f;
            #pragma unroll
            for (int e = 0; e < 8; ++e) {
                const uint2 pk = sw1[t*32 + g*8 + e];
                const float wx = __uint_as_float(pk.x << 16);
                const float wy = __uint_as_float(pk.x & 0xffff0000u);
                const float wz = __uint_as_float(pk.y << 16);
                const float bb = __uint_as_float(pk.y & 0xffff0000u);
                float h = bb + p0*wx + p1*wy + p2*wz;
                h = ELU(h);
                f[e] = f2bf(h);
            }
            if (t == 0) af0 = f; else af1 = f;
        }
        f32x4 hacc[4];
        #pragma unroll
        for (int nt = 0; nt < 4; ++nt) {
            f32x4 a; a[0] = b2c[nt]; a[1] = b2c[nt]; a[2] = b2c[nt]; a[3] = b2c[nt];
            const short8v bf0 = *(const short8v*)&sw2[((nt*2 + 0)*64 + lane) * 8];
            const short8v bf1 = *(const short8v*)&sw2[((nt*2 + 1)*64 + lane) * 8];
            a = MFMA32(af0, bf0, a);
            a = MFMA32(af1, bf1, a);
            hacc[nt] = a;
        }
        short8v a2 = (short8v)0;
        a2[0] = (short)xv.x; a2[1] = (short)xv.y;
        a2[2] = (short)xv.z; a2[3] = (short)xv.w;

        // ---- phase B: software-pipelined (bfrag/MFMA one tile ahead of dot) ----
        f32x4 z; z[0] = 0.f; z[1] = 0.f; z[2] = 0.f; z[3] = 0.f;
        float q0a[8], q1a[8];
        short8v bf_c = (short8v)0;
        #pragma unroll
        for (int q = 0; q < 4; ++q) bf_c[q] = f2bf(ELU(hacc[0][q]));
        f32x4 fx_c = MFMA32(a2, bf_c, z);
        #pragma unroll
        for (int u = 0; u < 8; ++u) {
            f32x4 fx_n;
            if (u < 7) {
                const int un = u + 1;
                short8v bf_n = (short8v)0;
                if (un < 4) {
                    #pragma unroll
                    for (int q = 0; q < 4; ++q) bf_n[q] = f2bf(ELU(hacc[un][q]));
                } else {
                    #pragma unroll
                    for (int e = 0; e < 4; ++e)
                        bf_n[e] = f2bf(sfc[(g*4 + e)*64 + (((un - 4)*16 + s) ^ g8)]);
                }
                fx_n = MFMA32(a2, bf_n, z);
            }
            const float a0 = __uint_as_float(wp0[u].x << 16);
            const float a1 = __uint_as_float(wp0[u].x & 0xffff0000u);
            const float a2f = __uint_as_float(wp0[u].y << 16);
            const float a3 = __uint_as_float(wp0[u].y & 0xffff0000u);
            const float c0 = __uint_as_float(wp1[u].x << 16);
            const float c1 = __uint_as_float(wp1[u].x & 0xffff0000u);
            const float c2 = __uint_as_float(wp1[u].y << 16);
            const float c3 = __uint_as_float(wp1[u].y & 0xffff0000u);
            q0a[u] = fx_c[0]*a0 + fx_c[1]*a1 + fx_c[2]*a2f + fx_c[3]*a3;
            q1a[u] = fx_c[0]*c0 + fx_c[1]*c1 + fx_c[2]*c2 + fx_c[3]*c3;
            if (u < 7) fx_c = fx_n;
        }
        // ---- batched xor-16 ----
        #pragma unroll
        for (int u = 0; u < 8; ++u) {
            q0a[u] += __shfl_xor(q0a[u], 16);
            q1a[u] += __shfl_xor(q1a[u], 16);
        }
        // ---- xor-32 via permlane32_swap ----
        #pragma unroll
        for (int u = 0; u < 8; ++u) {
            q0a[u] = xor32_add(q0a[u]);
            q1a[u] = xor32_add(q1a[u]);
        }
        if (lane < 16) {   // g==0, s=lane
            #pragma unroll
            for (int u = 0; u < 8; ++u) {
                const int c = u*16 + s;
                const unsigned pk = packbf(q0a[u] + sbdw[2*c], q1a[u] + sbdw[2*c + 1]);
                *(unsigned*)&tmpbf[(size_t)pt*256 + 2*c] = pk;
            }
        }
    }
}

// ---------------- Kernel 3: out = elu(tmp_bf16 @ wpw^T + bpw) via MFMA ----------------
__global__ __launch_bounds__(256) void k_out(
    const unsigned short* __restrict__ tmp, const float* __restrict__ wpw,
    const float* __restrict__ bpw, float* __restrict__ out)
{
    __shared__ unsigned sb[16384];   // 64KB: [n][chunk cb^(n&7)][wi]
    const int tid = threadIdx.x;
    for (int e = tid; e < 16384; e += 256) {
        const int n = e >> 7, kw = e & 127;
        const int cb = kw >> 2, wi = kw & 3;
        const unsigned lo = (unsigned)(unsigned short)f2bf(wpw[n*256 + 2*kw]);
        const unsigned hi = (unsigned)(unsigned short)f2bf(wpw[n*256 + 2*kw + 1]);
        sb[n*128 + ((cb ^ (n & 7)) << 2) + wi] = lo | (hi << 16);
    }
    __syncthreads();

    const int lane = tid & 63, wave = tid >> 6;
    const int g = lane >> 4, s = lane & 15;
    const int row = blockIdx.x * 64 + wave * 16 + s;

    f32x4 acc[8];
    #pragma unroll
    for (int nt = 0; nt < 8; ++nt) {
        const float b = bpw[nt*16 + s];
        acc[nt][0] = b; acc[nt][1] = b; acc[nt][2] = b; acc[nt][3] = b;
    }

    const unsigned short* arow = tmp + (size_t)row * 256 + g*8;
    short8v pa = *(const short8v*)(arow);

    #pragma unroll
    for (int kk = 0; kk < 8; ++kk) {
        const short8v a = pa;
        if (kk < 7) pa = *(const short8v*)(arow + (kk+1)*32);
        #pragma unroll
        for (int nt = 0; nt < 8; ++nt) {
            const short8v bf = *(const short8v*)&sb[(nt*16 + s)*128 + (((kk*4 + g) ^ (s & 7)) << 2)];
            acc[nt] = MFMA32(a, bf, acc[nt]);
        }
    }
    const int rbase = blockIdx.x * 64 + wave * 16 + 4*g;
    #pragma unroll
    for (int nt = 0; nt < 8; ++nt)
        #pragma unroll
        for (int q = 0; q < 4; ++q)
            out[(size_t)(rbase + q) * 128 + nt*16 + s] = ELU(acc[nt][q]);
}

extern "C" void kernel_launch(void* const* d_in, const int* in_sizes, int n_in,
                              void* d_out, int out_size, void* d_ws, size_t ws_size,
                              hipStream_t stream)
{
    (void)in_sizes; (void)n_in; (void)out_size; (void)ws_size;
    const float* rep   = (const float*)d_in[0];
    const float* pts   = (const float*)d_in[1];
    const float* fts   = (const float*)d_in[2];
    const float* w1    = (const float*)d_in[3];
    const float* b1    = (const float*)d_in[4];
    const float* w2    = (const float*)d_in[5];
    const float* b2    = (const float*)d_in[6];
    const float* wconv = (const float*)d_in[7];
    const float* bconv = (const float*)d_in[8];
    const float* wdep1 = (const float*)d_in[9];
    const float* bdep1 = (const float*)d_in[10];
    const float* wdep2 = (const float*)d_in[11];
    const float* bdep2 = (const float*)d_in[12];
    const float* wdw   = (const float*)d_in[13];
    const float* bdw   = (const float*)d_in[14];
    const float* wpw   = (const float*)d_in[15];
    const float* bpw   = (const float*)d_in[16];
    float* out  = (float*)d_out;
    unsigned short* x2bf  = (unsigned short*)d_ws;                       // 16.8 MB
    unsigned short* tmpbf = (unsigned short*)((char*)d_ws + (size_t)32 * 1024 * 1024); // 16.8 MB

    hipFuncSetAttribute((const void*)k_xform, hipFuncAttributeMaxDynamicSharedMemorySize, XW_TOTAL*4);

    k_xform<<<dim3(512), dim3(256), XW_TOTAL*4, stream>>>(rep, pts, wconv, bconv, wdep1, bdep1, wdep2, bdep2, x2bf);
    k_feat <<<dim3(768), dim3(256), 0, stream>>>(rep, pts, fts, w1, b1, w2, b2, wdw, bdw, x2bf, tmpbf);
    k_out  <<<dim3(512), dim3(256), 0, stream>>>(tmpbf, wpw, bpw, out);
}